// Round 6
// baseline (356.044 us; speedup 1.0000x reference)
//
#include <hip/hip_runtime.h>
#include <hip/hip_bf16.h>
#include <cstdint>
#include <cstddef>

#define NTOK 8192
#define DH   2048
#define DF   1376
#define DFP  1408      // h row stride (K-padded for down-GEMM)
#define NE   8
#define CAP  1280

typedef __bf16 bf16x8 __attribute__((ext_vector_type(8)));
typedef float  f32x4  __attribute__((ext_vector_type(4)));

#define BARRIER() asm volatile("s_barrier" ::: "memory")
#define WAITV(n)  asm volatile("s_waitcnt vmcnt(" #n ")" ::: "memory")
#define SETPRIO(n) __builtin_amdgcn_s_setprio(n)

__device__ __forceinline__ uint32_t pk2(float a, float b) {
  float2 f; f.x = a; f.y = b;
  union { __hip_bfloat162 h; uint32_t u; } cv;
  cv.h = __float22bfloat162_rn(f);
  return cv.u;
}
__device__ __forceinline__ ushort bf16bits(float a) {
  return (ushort)(pk2(a, 0.f) & 0xFFFFu);
}
// async global->LDS, 16B/lane; lds ptr wave-uniform, HW adds lane*16
__device__ __forceinline__ void gload16(const ushort* g, ushort* l) {
  __builtin_amdgcn_global_load_lds(
      (const __attribute__((address_space(1))) uint32_t*)(const void*)g,
      (__attribute__((address_space(3))) uint32_t*)(void*)l,
      16, 0, 0);
}

// ---- rowpair-128B layout for BK=32 tiles (conflict-free b128 reads) ----
// element (row, k): pair p=row>>1, granule g=(row&1)*4 + k/8,
// byte = p*128 + ((g ^ (p&7)) << 4) + (k%8)*2
__device__ __forceinline__ void rp_src(int o, int& row, int& ko) {
  int p = o >> 7;
  int g = ((o >> 4) & 7) ^ (p & 7);
  row = p * 2 + (g >> 2);
  ko  = (g & 3) * 8;
}
__device__ __forceinline__ int rp_off(int row, int l4) {
  return ((row >> 1) << 7) + (((((row & 1) << 2) + l4) ^ ((row >> 1) & 7)) << 4);
}

// ---------------- routing ----------------
__global__ void routing_kernel(const int* __restrict__ idx, int* __restrict__ tok_slot,
                               int* __restrict__ tok_keep) {
  __shared__ int cnt[256][NE];
  const int t = threadIdx.x;
  for (int s = t; s < NE * CAP; s += 256) tok_slot[s] = -1;
  unsigned long long cA = 0ull, cB = 0ull;
  const int per = NTOK / 256, base = t * per;
  for (int i = 0; i < per; ++i) {
    int e = idx[base + i];
    unsigned long long inc = 1ull << ((e & 3) * 16);
    if (e < 4) cA += inc; else cB += inc;
  }
#pragma unroll
  for (int e = 0; e < 4; ++e) cnt[t][e]     = (int)((cA >> (e * 16)) & 0xFFFF);
#pragma unroll
  for (int e = 0; e < 4; ++e) cnt[t][4 + e] = (int)((cB >> (e * 16)) & 0xFFFF);
  __syncthreads();
  if (t < NE) {
    int run = 0;
    for (int i = 0; i < 256; ++i) { int c = cnt[i][t]; cnt[i][t] = run; run += c; }
  }
  __syncthreads();
  cA = 0ull; cB = 0ull;
#pragma unroll
  for (int e = 0; e < 4; ++e) cA |= (unsigned long long)(cnt[t][e] & 0xFFFF) << (e * 16);
#pragma unroll
  for (int e = 0; e < 4; ++e) cB |= (unsigned long long)(cnt[t][4 + e] & 0xFFFF) << (e * 16);
  for (int i = 0; i < per; ++i) {
    int token = base + i;
    int e = idx[token];
    int sh = (e & 3) * 16;
    int r = (int)(((e < 4 ? cA : cB) >> sh) & 0xFFFF);
    unsigned long long inc = 1ull << sh;
    if (e < 4) cA += inc; else cB += inc;
    bool keep = (r < CAP);
    tok_keep[token] = keep ? 1 : 0;
    if (keep) tok_slot[e * CAP + r] = token;
  }
}

// ---------------- y rows for dropped tokens -> 0 ----------------
__global__ void zero_dropped(const int* __restrict__ keep, float* __restrict__ y) {
  if (keep[blockIdx.x]) return;
  float4 z = {0.f, 0.f, 0.f, 0.f};
  float* p = y + (size_t)blockIdx.x * DH + threadIdx.x * 8;
  *(float4*)p = z;
  *(float4*)(p + 4) = z;
}

// ---------------- x f32 -> bf16 ----------------
__global__ void convert_x(const float* __restrict__ x, ushort* __restrict__ xb) {
  int i = (blockIdx.x * 256 + threadIdx.x) * 8;
  float4 a = *(const float4*)(x + i);
  float4 b = *(const float4*)(x + i + 4);
  uint4 p = { pk2(a.x, a.y), pk2(a.z, a.w), pk2(b.x, b.y), pk2(b.z, b.w) };
  *(uint4*)(xb + i) = p;
}

// ---------------- w [E][K][N] f32 -> [E][N][K] bf16 ----------------
__global__ __launch_bounds__(256) void transpose_cvt(
    const float* __restrict__ in, ushort* __restrict__ out, int K, int N) {
  __shared__ ushort T[64][72];
  const int tid = threadIdx.x;
  const int n0 = blockIdx.x * 64, k0 = blockIdx.y * 64;
  const size_t eoff_in  = (size_t)blockIdx.z * K * N;
  const size_t eoff_out = (size_t)blockIdx.z * N * K;
  const int kr = tid >> 4;
  const int nc = (tid & 15) * 4;
#pragma unroll
  for (int it = 0; it < 4; ++it) {
    int k = k0 + kr + it * 16;
    int n = n0 + nc;
    float4 v = {0.f, 0.f, 0.f, 0.f};
    if (k < K && n + 4 <= N) v = *(const float4*)(in + eoff_in + (size_t)k * N + n);
    T[nc + 0][kr + it * 16] = bf16bits(v.x);
    T[nc + 1][kr + it * 16] = bf16bits(v.y);
    T[nc + 2][kr + it * 16] = bf16bits(v.z);
    T[nc + 3][kr + it * 16] = bf16bits(v.w);
  }
  __syncthreads();
  const int nr = tid >> 2;
  const int kc = tid & 3;
#pragma unroll
  for (int it = 0; it < 2; ++it) {
    int kloc = kc * 16 + it * 8;
    int n = n0 + nr, k = k0 + kloc;
    if (n < N && k + 8 <= K)
      *(uint4*)(out + eoff_out + (size_t)n * K + k) = *(const uint4*)&T[nr][kloc];
  }
}

// ---------------- zero h pad cols [DF, DFP) ----------------
__global__ void pad_h(ushort* __restrict__ h) {
  int idx = blockIdx.x * 512 + threadIdx.x;   // 40960 total
  int row = idx >> 2, q = idx & 3;
  uint4 z = {0u, 0u, 0u, 0u};
  *(uint4*)(h + (size_t)row * DFP + DF + q * 8) = z;
}

// ======================================================================
// GEMM1 (256Mx128N, BK=32, QUAD-buffer, rowpair-128B layout, 8 waves
// 4Mx2N of 64x64 dual-B): h = silu(Xe*Wg) .* (Xe*Wu)
// ONE barrier per K-tile: {12 ds_read | 4 gload(t+3) | 32 MFMA | vmcnt | bar}
// LDS 128KB: A[4][16KB]@0, Bg[4][8KB]@64K, Bu[4][8KB]@96K
// vmcnt: 4 loads/tile, steady WAITV(8); tail 4/0.
// ======================================================================
__global__ __launch_bounds__(512, 1) void gemm_gateup3(
    const ushort* __restrict__ xb, const ushort* __restrict__ wgt,
    const ushort* __restrict__ wut, const int* __restrict__ tok_slot,
    ushort* __restrict__ h)
{
  __shared__ __align__(16) char sm[131072];
  const int tid = threadIdx.x, lane = tid & 63, wid = tid >> 6;
  const int wr = wid >> 1, wc = wid & 1;
  const int l15 = lane & 15, l4 = lane >> 4;

  // XCD swizzle: 440 blocks = 8 XCDs x 55 (one expert: 5 mt x 11 nt)
  int wgid = (blockIdx.x & 7) * 55 + (blockIdx.x >> 3);
  const int e = wgid / 55;
  const int rem = wgid - e * 55;
  const int mt = rem / 11, nt = rem - (rem / 11) * 11;
  const int n0 = nt * 128;

  // staging sources (inverse rowpair map on per-lane global addr)
  const ushort* srcA[2]; const ushort* srcBg; const ushort* srcBu;
#pragma unroll
  for (int c = 0; c < 2; ++c) {
    int o = c * 8192 + wid * 1024 + lane * 16;
    int row, ko; rp_src(o, row, ko);
    int tk = tok_slot[e * CAP + mt * 256 + row];
    if (tk < 0) tk = 0;                        // finite garbage; discarded
    srcA[c] = xb + (size_t)tk * DH + ko;
  }
  {
    int o = wid * 1024 + lane * 16;
    int row, ko; rp_src(o, row, ko);
    int n = n0 + row; if (n > DF - 1) n = DF - 1;
    srcBg = wgt + ((size_t)e * DF + n) * DH + ko;
    srcBu = wut + ((size_t)e * DF + n) * DH + ko;
  }
  int aoff[4], boff[4];
#pragma unroll
  for (int i = 0; i < 4; ++i) aoff[i] = rp_off(wr * 64 + i * 16 + l15, l4);
#pragma unroll
  for (int j = 0; j < 4; ++j) boff[j] = rp_off(wc * 64 + j * 16 + l15, l4);
  const int dstw = wid * 1024;

  f32x4 accG[4][4], accU[4][4];
#pragma unroll
  for (int i = 0; i < 4; ++i)
#pragma unroll
    for (int j = 0; j < 4; ++j) {
      accG[i][j] = (f32x4){0.f, 0.f, 0.f, 0.f};
      accU[i][j] = (f32x4){0.f, 0.f, 0.f, 0.f};
    }

  const int NT = DH / 32;  // 64
#pragma unroll
  for (int t0 = 0; t0 < 3; ++t0) {
    int kk = t0 * 32;
    gload16(srcA[0] + kk, (ushort*)(sm + t0 * 16384 + dstw));
    gload16(srcA[1] + kk, (ushort*)(sm + t0 * 16384 + 8192 + dstw));
    gload16(srcBg   + kk, (ushort*)(sm + 65536 + t0 * 8192 + dstw));
    gload16(srcBu   + kk, (ushort*)(sm + 98304 + t0 * 8192 + dstw));
  }
  WAITV(8);
  BARRIER();

  for (int t = 0; t < NT; ++t) {
    const int r = t & 3, w = (t + 3) & 3;
    char* Ab  = sm + r * 16384;
    char* Bgb = sm + 65536 + r * 8192;
    char* Bub = sm + 98304 + r * 8192;
    bf16x8 a[4], bg[4], bu[4];
#pragma unroll
    for (int i = 0; i < 4; ++i) a[i]  = *(const bf16x8*)(Ab + aoff[i]);
#pragma unroll
    for (int j = 0; j < 4; ++j) bg[j] = *(const bf16x8*)(Bgb + boff[j]);
#pragma unroll
    for (int j = 0; j < 4; ++j) bu[j] = *(const bf16x8*)(Bub + boff[j]);
    if (t + 3 < NT) {
      int kk = (t + 3) * 32;
      gload16(srcA[0] + kk, (ushort*)(sm + w * 16384 + dstw));
      gload16(srcA[1] + kk, (ushort*)(sm + w * 16384 + 8192 + dstw));
      gload16(srcBg   + kk, (ushort*)(sm + 65536 + w * 8192 + dstw));
      gload16(srcBu   + kk, (ushort*)(sm + 98304 + w * 8192 + dstw));
    }
    SETPRIO(1);
#pragma unroll
    for (int j = 0; j < 4; ++j)
#pragma unroll
      for (int i = 0; i < 4; ++i)
        accG[i][j] = __builtin_amdgcn_mfma_f32_16x16x32_bf16(a[i], bg[j], accG[i][j], 0, 0, 0);
#pragma unroll
    for (int j = 0; j < 4; ++j)
#pragma unroll
      for (int i = 0; i < 4; ++i)
        accU[i][j] = __builtin_amdgcn_mfma_f32_16x16x32_bf16(a[i], bu[j], accU[i][j], 0, 0, 0);
    SETPRIO(0);
    if (t + 3 < NT)      { WAITV(8); }
    else if (t + 2 < NT) { WAITV(4); }
    else if (t + 1 < NT) { WAITV(0); }
    BARRIER();
  }
  // epilogue: SwiGLU -> h (stride DFP)
  const size_t rowbase = (size_t)(e * CAP + mt * 256 + wr * 64);
#pragma unroll
  for (int j = 0; j < 4; ++j) {
    int col = n0 + wc * 64 + j * 16 + l15;
    if (col < DF) {
#pragma unroll
      for (int i = 0; i < 4; ++i)
#pragma unroll
        for (int r2 = 0; r2 < 4; ++r2) {
          size_t row = rowbase + i * 16 + l4 * 4 + r2;
          float gv = accG[i][j][r2], uv = accU[i][j][r2];
          h[row * DFP + col] = bf16bits(gv / (1.f + __expf(-gv)) * uv);
        }
    }
  }
}

// ======================================================================
// GEMM2 (256Mx128N, BK=32, QUAD-buffer, rowpair-128B layout, 8 waves
// 4Mx2N of 64x64): y[token] = (H*Wd)*score
// ONE barrier per K-tile: {8 ds_read | 3 gload(t+3) | 16 MFMA | vmcnt | bar}
// LDS 98KB: A[4][16KB]@0, B[4][8KB]@64K, tokc@96K, scc@97K
// vmcnt: 3 loads/tile, steady WAITV(6); tail 3/0.
// ======================================================================
__global__ __launch_bounds__(512, 1) void gemm_down3(
    const ushort* __restrict__ h, const ushort* __restrict__ wdt,
    const int* __restrict__ tok_slot, const float* __restrict__ scores,
    float* __restrict__ y)
{
  __shared__ __align__(16) char sm[100352];
  int* tokc = (int*)(sm + 98304);
  float* scc = (float*)(sm + 99328);
  const int tid = threadIdx.x, lane = tid & 63, wid = tid >> 6;
  const int wr = wid >> 1, wc = wid & 1;
  const int l15 = lane & 15, l4 = lane >> 4;

  // XCD swizzle: 640 blocks = 8 XCDs x 80 (one expert: 5 mt x 16 nt)
  int wgid = (blockIdx.x & 7) * 80 + (blockIdx.x >> 3);
  const int e = wgid / 80;
  const int rem = wgid - e * 80;
  const int mt = rem / 16, nt = rem & 15;
  const int n0 = nt * 128;

  if (tid < 256) {
    int tk = tok_slot[e * CAP + mt * 256 + tid];
    tokc[tid] = tk;
    scc[tid] = (tk >= 0) ? scores[tk] : 0.f;
  }
  __syncthreads();

  const size_t hrow0 = (size_t)(e * CAP + mt * 256);
  const ushort* srcA[2]; const ushort* srcB;
#pragma unroll
  for (int c = 0; c < 2; ++c) {
    int o = c * 8192 + wid * 1024 + lane * 16;
    int row, ko; rp_src(o, row, ko);
    srcA[c] = h + (hrow0 + row) * DFP + ko;
  }
  {
    int o = wid * 1024 + lane * 16;
    int row, ko; rp_src(o, row, ko);
    srcB = wdt + ((size_t)e * DH + n0 + row) * DF + ko;   // stride DF
  }
  int aoff[4], boff[4];
#pragma unroll
  for (int i = 0; i < 4; ++i) aoff[i] = rp_off(wr * 64 + i * 16 + l15, l4);
#pragma unroll
  for (int j = 0; j < 4; ++j) boff[j] = rp_off(wc * 64 + j * 16 + l15, l4);
  const int dstw = wid * 1024;

  f32x4 acc[4][4];
#pragma unroll
  for (int i = 0; i < 4; ++i)
#pragma unroll
    for (int j = 0; j < 4; ++j) acc[i][j] = (f32x4){0.f, 0.f, 0.f, 0.f};

  const int NT = DFP / 32;  // 44 (A pad cols zero; B tail killed by A zeros)
#pragma unroll
  for (int t0 = 0; t0 < 3; ++t0) {
    int kk = t0 * 32;
    gload16(srcA[0] + kk, (ushort*)(sm + t0 * 16384 + dstw));
    gload16(srcA[1] + kk, (ushort*)(sm + t0 * 16384 + 8192 + dstw));
    gload16(srcB    + kk, (ushort*)(sm + 65536 + t0 * 8192 + dstw));
  }
  WAITV(6);
  BARRIER();

  for (int t = 0; t < NT; ++t) {
    const int r = t & 3, w = (t + 3) & 3;
    char* Ab = sm + r * 16384;
    char* Bb = sm + 65536 + r * 8192;
    bf16x8 a[4], b[4];
#pragma unroll
    for (int i = 0; i < 4; ++i) a[i] = *(const bf16x8*)(Ab + aoff[i]);
#pragma unroll
    for (int j = 0; j < 4; ++j) b[j] = *(const bf16x8*)(Bb + boff[j]);
    if (t + 3 < NT) {
      int kk = (t + 3) * 32;
      gload16(srcA[0] + kk, (ushort*)(sm + w * 16384 + dstw));
      gload16(srcA[1] + kk, (ushort*)(sm + w * 16384 + 8192 + dstw));
      gload16(srcB    + kk, (ushort*)(sm + 65536 + w * 8192 + dstw));
    }
    SETPRIO(1);
#pragma unroll
    for (int j = 0; j < 4; ++j)
#pragma unroll
      for (int i = 0; i < 4; ++i)
        acc[i][j] = __builtin_amdgcn_mfma_f32_16x16x32_bf16(a[i], b[j], acc[i][j], 0, 0, 0);
    SETPRIO(0);
    if (t + 3 < NT)      { WAITV(6); }
    else if (t + 2 < NT) { WAITV(3); }
    else if (t + 1 < NT) { WAITV(0); }
    BARRIER();
  }
  // epilogue: scatter * score
  int tkr[4][4]; float sr[4][4];
#pragma unroll
  for (int i = 0; i < 4; ++i)
#pragma unroll
    for (int r = 0; r < 4; ++r) {
      int rl = wr * 64 + i * 16 + l4 * 4 + r;
      tkr[i][r] = tokc[rl];
      sr[i][r]  = scc[rl];
    }
#pragma unroll
  for (int j = 0; j < 4; ++j) {
    int col = n0 + wc * 64 + j * 16 + l15;
#pragma unroll
    for (int i = 0; i < 4; ++i)
#pragma unroll
      for (int r = 0; r < 4; ++r)
        if (tkr[i][r] >= 0)
          y[(size_t)tkr[i][r] * DH + col] = acc[i][j][r] * sr[i][r];
  }
}

extern "C" void kernel_launch(void* const* d_in, const int* in_sizes, int n_in,
                              void* d_out, int out_size, void* d_ws, size_t ws_size,
                              hipStream_t stream) {
  const float* x   = (const float*)d_in[0];
  const int*   idx = (const int*)d_in[1];
  const float* sc  = (const float*)d_in[2];
  const float* wg  = (const float*)d_in[3];
  const float* wu  = (const float*)d_in[4];
  const float* wd  = (const float*)d_in[5];
  float* y = (float*)d_out;

  // ws layout (~152.6 MB; wdt reuses wgt region after gateup)
  const size_t OFF_KEEP = 40960;                       // tok_slot [0,40960)
  const size_t OFF_H    = 73728;                       // keep [40960,73728)
  const size_t SZ_H     = (size_t)NE * CAP * DFP * 2;  // 28,835,840
  const size_t OFF_XB   = OFF_H + SZ_H;                // 28,909,568
  const size_t SZ_XB    = (size_t)NTOK * DH * 2;       // 33,554,432
  const size_t OFF_WGT  = OFF_XB + SZ_XB;              // 62,464,000
  const size_t SZ_W     = (size_t)NE * DH * DF * 2;    // 45,088,768
  const size_t OFF_WUT  = OFF_WGT + SZ_W;              // 107,552,768

  int* tok_slot = (int*)d_ws;
  int* tok_keep = (int*)((char*)d_ws + OFF_KEEP);
  ushort* hbuf = (ushort*)((char*)d_ws + OFF_H);
  ushort* xb   = (ushort*)((char*)d_ws + OFF_XB);
  ushort* wgt  = (ushort*)((char*)d_ws + OFF_WGT);
  ushort* wut  = (ushort*)((char*)d_ws + OFF_WUT);
  ushort* wdt  = wgt;   // dead after gateup

  hipLaunchKernelGGL(routing_kernel, dim3(1), dim3(256), 0, stream, idx, tok_slot, tok_keep);
  hipLaunchKernelGGL(zero_dropped, dim3(NTOK), dim3(256), 0, stream, tok_keep, y);
  hipLaunchKernelGGL(convert_x, dim3(NTOK * DH / 2048), dim3(256), 0, stream, x, xb);
  hipLaunchKernelGGL(transpose_cvt, dim3((DF + 63) / 64, DH / 64, NE), dim3(256), 0, stream,
                     wg, wgt, DH, DF);
  hipLaunchKernelGGL(transpose_cvt, dim3((DF + 63) / 64, DH / 64, NE), dim3(256), 0, stream,
                     wu, wut, DH, DF);
  hipLaunchKernelGGL(pad_h, dim3(80), dim3(512), 0, stream, hbuf);
  hipLaunchKernelGGL(gemm_gateup3, dim3(440), dim3(512), 0, stream,
                     xb, wgt, wut, tok_slot, hbuf);
  hipLaunchKernelGGL(transpose_cvt, dim3(DH / 64, (DF + 63) / 64, NE), dim3(256), 0, stream,
                     wd, wdt, DF, DH);
  hipLaunchKernelGGL(gemm_down3, dim3(640), dim3(512), 0, stream,
                     hbuf, wdt, tok_slot, sc, y);
}

// Round 7
// 349.344 us; speedup vs baseline: 1.0192x; 1.0192x over previous
//
#include <hip/hip_runtime.h>
#include <hip/hip_bf16.h>
#include <cstdint>
#include <cstddef>

#define NTOK 8192
#define DH   2048
#define DF   1376
#define DFP  1408      // h row stride (K-padded for down-GEMM)
#define NE   8
#define CAP  1280

typedef __bf16 bf16x8 __attribute__((ext_vector_type(8)));
typedef float  f32x4  __attribute__((ext_vector_type(4)));

#define BARRIER() asm volatile("s_barrier" ::: "memory")
#define WAITV(n)  asm volatile("s_waitcnt vmcnt(" #n ")" ::: "memory")
#define LGKM0()   asm volatile("s_waitcnt lgkmcnt(0)" ::: "memory")
#define SCHED0()  __builtin_amdgcn_sched_barrier(0)
#define SETPRIO(n) __builtin_amdgcn_s_setprio(n)

__device__ __forceinline__ uint32_t pk2(float a, float b) {
  float2 f; f.x = a; f.y = b;
  union { __hip_bfloat162 h; uint32_t u; } cv;
  cv.h = __float22bfloat162_rn(f);
  return cv.u;
}
__device__ __forceinline__ ushort bf16bits(float a) {
  return (ushort)(pk2(a, 0.f) & 0xFFFFu);
}
// async global->LDS, 16B/lane; lds ptr wave-uniform, HW adds lane*16
__device__ __forceinline__ void gload16(const ushort* g, ushort* l) {
  __builtin_amdgcn_global_load_lds(
      (const __attribute__((address_space(1))) uint32_t*)(const void*)g,
      (__attribute__((address_space(3))) uint32_t*)(void*)l,
      16, 0, 0);
}

// ---- rowpair-128B layout for BK=32 tiles (conflict-free b128 reads) ----
// element (row, k): pair p=row>>1, granule g=(row&1)*4 + k/8,
// byte = p*128 + ((g ^ (p&7)) << 4) + (k%8)*2
__device__ __forceinline__ void rp_src(int o, int& row, int& ko) {
  int p = o >> 7;
  int g = ((o >> 4) & 7) ^ (p & 7);
  row = p * 2 + (g >> 2);
  ko  = (g & 3) * 8;
}
__device__ __forceinline__ int rp_off(int row, int l4) {
  return ((row >> 1) << 7) + (((((row & 1) << 2) + l4) ^ ((row >> 1) & 7)) << 4);
}

// ---------------- routing ----------------
__global__ void routing_kernel(const int* __restrict__ idx, int* __restrict__ tok_slot,
                               int* __restrict__ tok_keep) {
  __shared__ int cnt[256][NE];
  const int t = threadIdx.x;
  for (int s = t; s < NE * CAP; s += 256) tok_slot[s] = -1;
  unsigned long long cA = 0ull, cB = 0ull;
  const int per = NTOK / 256, base = t * per;
  for (int i = 0; i < per; ++i) {
    int e = idx[base + i];
    unsigned long long inc = 1ull << ((e & 3) * 16);
    if (e < 4) cA += inc; else cB += inc;
  }
#pragma unroll
  for (int e = 0; e < 4; ++e) cnt[t][e]     = (int)((cA >> (e * 16)) & 0xFFFF);
#pragma unroll
  for (int e = 0; e < 4; ++e) cnt[t][4 + e] = (int)((cB >> (e * 16)) & 0xFFFF);
  __syncthreads();
  if (t < NE) {
    int run = 0;
    for (int i = 0; i < 256; ++i) { int c = cnt[i][t]; cnt[i][t] = run; run += c; }
  }
  __syncthreads();
  cA = 0ull; cB = 0ull;
#pragma unroll
  for (int e = 0; e < 4; ++e) cA |= (unsigned long long)(cnt[t][e] & 0xFFFF) << (e * 16);
#pragma unroll
  for (int e = 0; e < 4; ++e) cB |= (unsigned long long)(cnt[t][4 + e] & 0xFFFF) << (e * 16);
  for (int i = 0; i < per; ++i) {
    int token = base + i;
    int e = idx[token];
    int sh = (e & 3) * 16;
    int r = (int)(((e < 4 ? cA : cB) >> sh) & 0xFFFF);
    unsigned long long inc = 1ull << sh;
    if (e < 4) cA += inc; else cB += inc;
    bool keep = (r < CAP);
    tok_keep[token] = keep ? 1 : 0;
    if (keep) tok_slot[e * CAP + r] = token;
  }
}

// ---------------- y rows for dropped tokens -> 0 ----------------
__global__ void zero_dropped(const int* __restrict__ keep, float* __restrict__ y) {
  if (keep[blockIdx.x]) return;
  float4 z = {0.f, 0.f, 0.f, 0.f};
  float* p = y + (size_t)blockIdx.x * DH + threadIdx.x * 8;
  *(float4*)p = z;
  *(float4*)(p + 4) = z;
}

// ---------------- x f32 -> bf16 ----------------
__global__ void convert_x(const float* __restrict__ x, ushort* __restrict__ xb) {
  int i = (blockIdx.x * 256 + threadIdx.x) * 8;
  float4 a = *(const float4*)(x + i);
  float4 b = *(const float4*)(x + i + 4);
  uint4 p = { pk2(a.x, a.y), pk2(a.z, a.w), pk2(b.x, b.y), pk2(b.z, b.w) };
  *(uint4*)(xb + i) = p;
}

// ---------------- w [E][K][N] f32 -> [E][N][K] bf16 ----------------
__global__ __launch_bounds__(256) void transpose_cvt(
    const float* __restrict__ in, ushort* __restrict__ out, int K, int N) {
  __shared__ ushort T[64][72];
  const int tid = threadIdx.x;
  const int n0 = blockIdx.x * 64, k0 = blockIdx.y * 64;
  const size_t eoff_in  = (size_t)blockIdx.z * K * N;
  const size_t eoff_out = (size_t)blockIdx.z * N * K;
  const int kr = tid >> 4;
  const int nc = (tid & 15) * 4;
#pragma unroll
  for (int it = 0; it < 4; ++it) {
    int k = k0 + kr + it * 16;
    int n = n0 + nc;
    float4 v = {0.f, 0.f, 0.f, 0.f};
    if (k < K && n + 4 <= N) v = *(const float4*)(in + eoff_in + (size_t)k * N + n);
    T[nc + 0][kr + it * 16] = bf16bits(v.x);
    T[nc + 1][kr + it * 16] = bf16bits(v.y);
    T[nc + 2][kr + it * 16] = bf16bits(v.z);
    T[nc + 3][kr + it * 16] = bf16bits(v.w);
  }
  __syncthreads();
  const int nr = tid >> 2;
  const int kc = tid & 3;
#pragma unroll
  for (int it = 0; it < 2; ++it) {
    int kloc = kc * 16 + it * 8;
    int n = n0 + nr, k = k0 + kloc;
    if (n < N && k + 8 <= K)
      *(uint4*)(out + eoff_out + (size_t)n * K + k) = *(const uint4*)&T[nr][kloc];
  }
}

// ---------------- zero h pad cols [DF, DFP) ----------------
__global__ void pad_h(ushort* __restrict__ h) {
  int idx = blockIdx.x * 512 + threadIdx.x;   // 40960 total
  int row = idx >> 2, q = idx & 3;
  uint4 z = {0u, 0u, 0u, 0u};
  *(uint4*)(h + (size_t)row * DFP + DF + q * 8) = z;
}

// ======================================================================
// GEMM1 (256Mx128N, BK=32, QUAD-buffer, rowpair-128B layout, 8 waves
// 4Mx2N of 64x64 dual-B): h = silu(Xe*Wg) .* (Xe*Wu)
// m201 phase discipline, 2 phases per K-tile:
//  ph1: {rd a[4],bg[4] | gload A(t+3)x2 | SBAR | lgkm0 | 16 G-MFMA | SBAR}
//  ph2: {rd bu[4] | gload Bg,Bu(t+3) | vmcnt(8) | SBAR | lgkm0 | 16 U-MFMA | SBAR}
// LDS 128KB: A[4][16KB]@0, Bg[4][8KB]@64K, Bu[4][8KB]@96K
// vmcnt ladder: steady 8 (4 loads/tile, 3 deep); tail 4/0.
// ======================================================================
__global__ __launch_bounds__(512, 1) void gemm_gateup3(
    const ushort* __restrict__ xb, const ushort* __restrict__ wgt,
    const ushort* __restrict__ wut, const int* __restrict__ tok_slot,
    ushort* __restrict__ h)
{
  __shared__ __align__(16) char sm[131072];
  const int tid = threadIdx.x, lane = tid & 63, wid = tid >> 6;
  const int wr = wid >> 1, wc = wid & 1;
  const int l15 = lane & 15, l4 = lane >> 4;

  // XCD swizzle: 440 blocks = 8 XCDs x 55 (one expert: 5 mt x 11 nt)
  int wgid = (blockIdx.x & 7) * 55 + (blockIdx.x >> 3);
  const int e = wgid / 55;
  const int rem = wgid - e * 55;
  const int mt = rem / 11, nt = rem - (rem / 11) * 11;
  const int n0 = nt * 128;

  // staging sources (inverse rowpair map on per-lane global addr)
  const ushort* srcA[2]; const ushort* srcBg; const ushort* srcBu;
#pragma unroll
  for (int c = 0; c < 2; ++c) {
    int o = c * 8192 + wid * 1024 + lane * 16;
    int row, ko; rp_src(o, row, ko);
    int tk = tok_slot[e * CAP + mt * 256 + row];
    if (tk < 0) tk = 0;                        // finite garbage; discarded
    srcA[c] = xb + (size_t)tk * DH + ko;
  }
  {
    int o = wid * 1024 + lane * 16;
    int row, ko; rp_src(o, row, ko);
    int n = n0 + row; if (n > DF - 1) n = DF - 1;
    srcBg = wgt + ((size_t)e * DF + n) * DH + ko;
    srcBu = wut + ((size_t)e * DF + n) * DH + ko;
  }
  int aoff[4], boff[4];
#pragma unroll
  for (int i = 0; i < 4; ++i) aoff[i] = rp_off(wr * 64 + i * 16 + l15, l4);
#pragma unroll
  for (int j = 0; j < 4; ++j) boff[j] = rp_off(wc * 64 + j * 16 + l15, l4);
  const int dstw = wid * 1024;

  f32x4 accG[4][4], accU[4][4];
#pragma unroll
  for (int i = 0; i < 4; ++i)
#pragma unroll
    for (int j = 0; j < 4; ++j) {
      accG[i][j] = (f32x4){0.f, 0.f, 0.f, 0.f};
      accU[i][j] = (f32x4){0.f, 0.f, 0.f, 0.f};
    }

  const int NT = DH / 32;  // 64
#pragma unroll
  for (int t0 = 0; t0 < 3; ++t0) {
    int kk = t0 * 32;
    gload16(srcA[0] + kk, (ushort*)(sm + t0 * 16384 + dstw));
    gload16(srcA[1] + kk, (ushort*)(sm + t0 * 16384 + 8192 + dstw));
    gload16(srcBg   + kk, (ushort*)(sm + 65536 + t0 * 8192 + dstw));
    gload16(srcBu   + kk, (ushort*)(sm + 98304 + t0 * 8192 + dstw));
  }
  WAITV(8);
  BARRIER();

  for (int t = 0; t < NT; ++t) {
    const int r = t & 3, w = (t + 3) & 3;
    char* Ab  = sm + r * 16384;
    char* Bgb = sm + 65536 + r * 8192;
    char* Bub = sm + 98304 + r * 8192;
    const int kk = (t + 3) * 32;
    bf16x8 a[4], bg[4], bu[4];
    // ---- ph1: reads + A prefetch | SBAR | lgkm0 | 16 G-MFMA | SBAR
#pragma unroll
    for (int i = 0; i < 4; ++i) a[i]  = *(const bf16x8*)(Ab + aoff[i]);
#pragma unroll
    for (int j = 0; j < 4; ++j) bg[j] = *(const bf16x8*)(Bgb + boff[j]);
    if (t + 3 < NT) {
      gload16(srcA[0] + kk, (ushort*)(sm + w * 16384 + dstw));
      gload16(srcA[1] + kk, (ushort*)(sm + w * 16384 + 8192 + dstw));
    }
    BARRIER();
    LGKM0(); SCHED0();
    SETPRIO(1);
#pragma unroll
    for (int j = 0; j < 4; ++j)
#pragma unroll
      for (int i = 0; i < 4; ++i)
        accG[i][j] = __builtin_amdgcn_mfma_f32_16x16x32_bf16(a[i], bg[j], accG[i][j], 0, 0, 0);
    SETPRIO(0); SCHED0();
    BARRIER();
    // ---- ph2: reads + B prefetch | vmcnt | SBAR | lgkm0 | 16 U-MFMA | SBAR
#pragma unroll
    for (int j = 0; j < 4; ++j) bu[j] = *(const bf16x8*)(Bub + boff[j]);
    if (t + 3 < NT) {
      gload16(srcBg + kk, (ushort*)(sm + 65536 + w * 8192 + dstw));
      gload16(srcBu + kk, (ushort*)(sm + 98304 + w * 8192 + dstw));
    }
    if (t + 3 < NT)      { WAITV(8); }
    else if (t + 2 < NT) { WAITV(4); }
    else if (t + 1 < NT) { WAITV(0); }
    BARRIER();
    LGKM0(); SCHED0();
    SETPRIO(1);
#pragma unroll
    for (int j = 0; j < 4; ++j)
#pragma unroll
      for (int i = 0; i < 4; ++i)
        accU[i][j] = __builtin_amdgcn_mfma_f32_16x16x32_bf16(a[i], bu[j], accU[i][j], 0, 0, 0);
    SETPRIO(0); SCHED0();
    BARRIER();
  }
  // epilogue: SwiGLU -> h (stride DFP)
  const size_t rowbase = (size_t)(e * CAP + mt * 256 + wr * 64);
#pragma unroll
  for (int j = 0; j < 4; ++j) {
    int col = n0 + wc * 64 + j * 16 + l15;
    if (col < DF) {
#pragma unroll
      for (int i = 0; i < 4; ++i)
#pragma unroll
        for (int r2 = 0; r2 < 4; ++r2) {
          size_t row = rowbase + i * 16 + l4 * 4 + r2;
          float gv = accG[i][j][r2], uv = accU[i][j][r2];
          h[row * DFP + col] = bf16bits(gv / (1.f + __expf(-gv)) * uv);
        }
    }
  }
}

// ======================================================================
// GEMM2 (256Mx128N, BK=32, QUAD-buffer, rowpair-128B layout, 8 waves
// 4Mx2N of 64x64): y[token] = (H*Wd)*score
// m201 phase discipline, 2 phases per K-tile (8-MFMA clusters):
//  ph1: {rd a[4],b[0..1] | gload A(t+3)x2 | SBAR | lgkm0 | 8 MFMA j01 | SBAR}
//  ph2: {rd b[2..3] | gload B(t+3) | vmcnt(6) | SBAR | lgkm0 | 8 MFMA j23 | SBAR}
// LDS 98KB: A[4][16KB]@0, B[4][8KB]@64K, tokc@96K, scc@97K
// vmcnt ladder: steady 6 (3 loads/tile, 3 deep); tail 3/0.
// ======================================================================
__global__ __launch_bounds__(512, 1) void gemm_down3(
    const ushort* __restrict__ h, const ushort* __restrict__ wdt,
    const int* __restrict__ tok_slot, const float* __restrict__ scores,
    float* __restrict__ y)
{
  __shared__ __align__(16) char sm[100352];
  int* tokc = (int*)(sm + 98304);
  float* scc = (float*)(sm + 99328);
  const int tid = threadIdx.x, lane = tid & 63, wid = tid >> 6;
  const int wr = wid >> 1, wc = wid & 1;
  const int l15 = lane & 15, l4 = lane >> 4;

  // XCD swizzle: 640 blocks = 8 XCDs x 80 (one expert: 5 mt x 16 nt)
  int wgid = (blockIdx.x & 7) * 80 + (blockIdx.x >> 3);
  const int e = wgid / 80;
  const int rem = wgid - e * 80;
  const int mt = rem / 16, nt = rem & 15;
  const int n0 = nt * 128;

  if (tid < 256) {
    int tk = tok_slot[e * CAP + mt * 256 + tid];
    tokc[tid] = tk;
    scc[tid] = (tk >= 0) ? scores[tk] : 0.f;
  }
  __syncthreads();

  const size_t hrow0 = (size_t)(e * CAP + mt * 256);
  const ushort* srcA[2]; const ushort* srcB;
#pragma unroll
  for (int c = 0; c < 2; ++c) {
    int o = c * 8192 + wid * 1024 + lane * 16;
    int row, ko; rp_src(o, row, ko);
    srcA[c] = h + (hrow0 + row) * DFP + ko;
  }
  {
    int o = wid * 1024 + lane * 16;
    int row, ko; rp_src(o, row, ko);
    srcB = wdt + ((size_t)e * DH + n0 + row) * DF + ko;   // stride DF
  }
  int aoff[4], boff[4];
#pragma unroll
  for (int i = 0; i < 4; ++i) aoff[i] = rp_off(wr * 64 + i * 16 + l15, l4);
#pragma unroll
  for (int j = 0; j < 4; ++j) boff[j] = rp_off(wc * 64 + j * 16 + l15, l4);
  const int dstw = wid * 1024;

  f32x4 acc[4][4];
#pragma unroll
  for (int i = 0; i < 4; ++i)
#pragma unroll
    for (int j = 0; j < 4; ++j) acc[i][j] = (f32x4){0.f, 0.f, 0.f, 0.f};

  const int NT = DFP / 32;  // 44 (A pad cols zero; B tail killed by A zeros)
#pragma unroll
  for (int t0 = 0; t0 < 3; ++t0) {
    int kk = t0 * 32;
    gload16(srcA[0] + kk, (ushort*)(sm + t0 * 16384 + dstw));
    gload16(srcA[1] + kk, (ushort*)(sm + t0 * 16384 + 8192 + dstw));
    gload16(srcB    + kk, (ushort*)(sm + 65536 + t0 * 8192 + dstw));
  }
  WAITV(6);
  BARRIER();

  for (int t = 0; t < NT; ++t) {
    const int r = t & 3, w = (t + 3) & 3;
    char* Ab = sm + r * 16384;
    char* Bb = sm + 65536 + r * 8192;
    const int kk = (t + 3) * 32;
    bf16x8 a[4], b[4];
    // ---- ph1
#pragma unroll
    for (int i = 0; i < 4; ++i) a[i] = *(const bf16x8*)(Ab + aoff[i]);
    b[0] = *(const bf16x8*)(Bb + boff[0]);
    b[1] = *(const bf16x8*)(Bb + boff[1]);
    if (t + 3 < NT) {
      gload16(srcA[0] + kk, (ushort*)(sm + w * 16384 + dstw));
      gload16(srcA[1] + kk, (ushort*)(sm + w * 16384 + 8192 + dstw));
    }
    BARRIER();
    LGKM0(); SCHED0();
    SETPRIO(1);
#pragma unroll
    for (int i = 0; i < 4; ++i) {
      acc[i][0] = __builtin_amdgcn_mfma_f32_16x16x32_bf16(a[i], b[0], acc[i][0], 0, 0, 0);
      acc[i][1] = __builtin_amdgcn_mfma_f32_16x16x32_bf16(a[i], b[1], acc[i][1], 0, 0, 0);
    }
    SETPRIO(0); SCHED0();
    BARRIER();
    // ---- ph2
    b[2] = *(const bf16x8*)(Bb + boff[2]);
    b[3] = *(const bf16x8*)(Bb + boff[3]);
    if (t + 3 < NT)
      gload16(srcB + kk, (ushort*)(sm + 65536 + w * 8192 + dstw));
    if (t + 3 < NT)      { WAITV(6); }
    else if (t + 2 < NT) { WAITV(3); }
    else if (t + 1 < NT) { WAITV(0); }
    BARRIER();
    LGKM0(); SCHED0();
    SETPRIO(1);
#pragma unroll
    for (int i = 0; i < 4; ++i) {
      acc[i][2] = __builtin_amdgcn_mfma_f32_16x16x32_bf16(a[i], b[2], acc[i][2], 0, 0, 0);
      acc[i][3] = __builtin_amdgcn_mfma_f32_16x16x32_bf16(a[i], b[3], acc[i][3], 0, 0, 0);
    }
    SETPRIO(0); SCHED0();
    BARRIER();
  }
  // epilogue: scatter * score
  int tkr[4][4]; float sr[4][4];
#pragma unroll
  for (int i = 0; i < 4; ++i)
#pragma unroll
    for (int r = 0; r < 4; ++r) {
      int rl = wr * 64 + i * 16 + l4 * 4 + r;
      tkr[i][r] = tokc[rl];
      sr[i][r]  = scc[rl];
    }
#pragma unroll
  for (int j = 0; j < 4; ++j) {
    int col = n0 + wc * 64 + j * 16 + l15;
#pragma unroll
    for (int i = 0; i < 4; ++i)
#pragma unroll
      for (int r = 0; r < 4; ++r)
        if (tkr[i][r] >= 0)
          y[(size_t)tkr[i][r] * DH + col] = acc[i][j][r] * sr[i][r];
  }
}

extern "C" void kernel_launch(void* const* d_in, const int* in_sizes, int n_in,
                              void* d_out, int out_size, void* d_ws, size_t ws_size,
                              hipStream_t stream) {
  const float* x   = (const float*)d_in[0];
  const int*   idx = (const int*)d_in[1];
  const float* sc  = (const float*)d_in[2];
  const float* wg  = (const float*)d_in[3];
  const float* wu  = (const float*)d_in[4];
  const float* wd  = (const float*)d_in[5];
  float* y = (float*)d_out;

  // ws layout (~152.6 MB; wdt reuses wgt region after gateup)
  const size_t OFF_KEEP = 40960;                       // tok_slot [0,40960)
  const size_t OFF_H    = 73728;                       // keep [40960,73728)
  const size_t SZ_H     = (size_t)NE * CAP * DFP * 2;  // 28,835,840
  const size_t OFF_XB   = OFF_H + SZ_H;                // 28,909,568
  const size_t SZ_XB    = (size_t)NTOK * DH * 2;       // 33,554,432
  const size_t OFF_WGT  = OFF_XB + SZ_XB;              // 62,464,000
  const size_t SZ_W     = (size_t)NE * DH * DF * 2;    // 45,088,768
  const size_t OFF_WUT  = OFF_WGT + SZ_W;              // 107,552,768

  int* tok_slot = (int*)d_ws;
  int* tok_keep = (int*)((char*)d_ws + OFF_KEEP);
  ushort* hbuf = (ushort*)((char*)d_ws + OFF_H);
  ushort* xb   = (ushort*)((char*)d_ws + OFF_XB);
  ushort* wgt  = (ushort*)((char*)d_ws + OFF_WGT);
  ushort* wut  = (ushort*)((char*)d_ws + OFF_WUT);
  ushort* wdt  = wgt;   // dead after gateup

  hipLaunchKernelGGL(routing_kernel, dim3(1), dim3(256), 0, stream, idx, tok_slot, tok_keep);
  hipLaunchKernelGGL(zero_dropped, dim3(NTOK), dim3(256), 0, stream, tok_keep, y);
  hipLaunchKernelGGL(convert_x, dim3(NTOK * DH / 2048), dim3(256), 0, stream, x, xb);
  hipLaunchKernelGGL(transpose_cvt, dim3((DF + 63) / 64, DH / 64, NE), dim3(256), 0, stream,
                     wg, wgt, DH, DF);
  hipLaunchKernelGGL(transpose_cvt, dim3((DF + 63) / 64, DH / 64, NE), dim3(256), 0, stream,
                     wu, wut, DH, DF);
  hipLaunchKernelGGL(pad_h, dim3(80), dim3(512), 0, stream, hbuf);
  hipLaunchKernelGGL(gemm_gateup3, dim3(440), dim3(512), 0, stream,
                     xb, wgt, wut, tok_slot, hbuf);
  hipLaunchKernelGGL(transpose_cvt, dim3(DH / 64, (DF + 63) / 64, NE), dim3(256), 0, stream,
                     wd, wdt, DF, DH);
  hipLaunchKernelGGL(gemm_down3, dim3(640), dim3(512), 0, stream,
                     hbuf, wdt, tok_slot, sc, y);
}

// Round 8
// 333.386 us; speedup vs baseline: 1.0680x; 1.0479x over previous
//
#include <hip/hip_runtime.h>
#include <hip/hip_bf16.h>
#include <cstdint>
#include <cstddef>

#define NTOK 8192
#define DH   2048
#define DF   1376      // 1376 % 32 == 0 -> no K-padding needed anywhere
#define NE   8
#define CAP  1280

typedef __bf16 bf16x8 __attribute__((ext_vector_type(8)));
typedef float  f32x4  __attribute__((ext_vector_type(4)));

#define BARRIER() asm volatile("s_barrier" ::: "memory")
#define WAITV(n)  asm volatile("s_waitcnt vmcnt(" #n ")" ::: "memory")
#define LGKM(n)   asm volatile("s_waitcnt lgkmcnt(" #n ")" ::: "memory")
#define SCHED0()  __builtin_amdgcn_sched_barrier(0)
#define SETPRIO(n) __builtin_amdgcn_s_setprio(n)

__device__ __forceinline__ uint32_t pk2(float a, float b) {
  float2 f; f.x = a; f.y = b;
  union { __hip_bfloat162 h; uint32_t u; } cv;
  cv.h = __float22bfloat162_rn(f);
  return cv.u;
}
__device__ __forceinline__ ushort bf16bits(float a) {
  return (ushort)(pk2(a, 0.f) & 0xFFFFu);
}
__device__ __forceinline__ void gload16(const ushort* g, ushort* l) {
  __builtin_amdgcn_global_load_lds(
      (const __attribute__((address_space(1))) uint32_t*)(const void*)g,
      (__attribute__((address_space(3))) uint32_t*)(void*)l,
      16, 0, 0);
}

// ---- rowpair-128B layout for BK=32 tiles (proven: 0 bank conflicts) ----
__device__ __forceinline__ void rp_src(int o, int& row, int& ko) {
  int p = o >> 7;
  int g = ((o >> 4) & 7) ^ (p & 7);
  row = p * 2 + (g >> 2);
  ko  = (g & 3) * 8;
}
__device__ __forceinline__ int rp_off(int row, int l4) {
  return ((row >> 1) << 7) + (((((row & 1) << 2) + l4) ^ ((row >> 1) & 7)) << 4);
}

// ---------------- routing ----------------
__global__ void routing_kernel(const int* __restrict__ idx, int* __restrict__ tok_slot,
                               int* __restrict__ tok_keep) {
  __shared__ int cnt[256][NE];
  const int t = threadIdx.x;
  for (int s = t; s < NE * CAP; s += 256) tok_slot[s] = -1;
  unsigned long long cA = 0ull, cB = 0ull;
  const int per = NTOK / 256, base = t * per;
  for (int i = 0; i < per; ++i) {
    int e = idx[base + i];
    unsigned long long inc = 1ull << ((e & 3) * 16);
    if (e < 4) cA += inc; else cB += inc;
  }
#pragma unroll
  for (int e = 0; e < 4; ++e) cnt[t][e]     = (int)((cA >> (e * 16)) & 0xFFFF);
#pragma unroll
  for (int e = 0; e < 4; ++e) cnt[t][4 + e] = (int)((cB >> (e * 16)) & 0xFFFF);
  __syncthreads();
  if (t < NE) {
    int run = 0;
    for (int i = 0; i < 256; ++i) { int c = cnt[i][t]; cnt[i][t] = run; run += c; }
  }
  __syncthreads();
  cA = 0ull; cB = 0ull;
#pragma unroll
  for (int e = 0; e < 4; ++e) cA |= (unsigned long long)(cnt[t][e] & 0xFFFF) << (e * 16);
#pragma unroll
  for (int e = 0; e < 4; ++e) cB |= (unsigned long long)(cnt[t][4 + e] & 0xFFFF) << (e * 16);
  for (int i = 0; i < per; ++i) {
    int token = base + i;
    int e = idx[token];
    int sh = (e & 3) * 16;
    int r = (int)(((e < 4 ? cA : cB) >> sh) & 0xFFFF);
    unsigned long long inc = 1ull << sh;
    if (e < 4) cA += inc; else cB += inc;
    bool keep = (r < CAP);
    tok_keep[token] = keep ? 1 : 0;
    if (keep) tok_slot[e * CAP + r] = token;
  }
}

// ---------------- x f32 -> bf16, fused zero of dropped y rows ----------------
__global__ void xconv_zero(const float* __restrict__ x, const int* __restrict__ keep,
                           ushort* __restrict__ xb, float* __restrict__ y) {
  const int row = blockIdx.x;
  const int c = threadIdx.x * 8;
  const size_t off = (size_t)row * DH + c;
  float4 a = *(const float4*)(x + off);
  float4 b = *(const float4*)(x + off + 4);
  uint4 p = { pk2(a.x, a.y), pk2(a.z, a.w), pk2(b.x, b.y), pk2(b.z, b.w) };
  *(uint4*)(xb + off) = p;
  if (!keep[row]) {
    float4 z = {0.f, 0.f, 0.f, 0.f};
    *(float4*)(y + off) = z;
    *(float4*)(y + off + 4) = z;
  }
}

// ---------------- all 3 weights: [E][K][N] f32 -> [E][N][K] bf16, one launch ----------------
__global__ __launch_bounds__(256) void transpose_all(
    const float* __restrict__ wg, const float* __restrict__ wu, const float* __restrict__ wd,
    ushort* __restrict__ wgt, ushort* __restrict__ wut, ushort* __restrict__ wdt) {
  const int z = blockIdx.z;
  const float* in; ushort* out; int K, N, eidx;
  if (z < 8)       { in = wg; out = wgt; K = DH; N = DF; eidx = z; }
  else if (z < 16) { in = wu; out = wut; K = DH; N = DF; eidx = z - 8; }
  else             { in = wd; out = wdt; K = DF; N = DH; eidx = z - 16; }
  const int n0 = blockIdx.x * 64, k0 = blockIdx.y * 64;
  if (n0 >= N || k0 >= K) return;
  __shared__ ushort T[64][72];
  const int tid = threadIdx.x;
  const size_t eoff_in  = (size_t)eidx * K * N;
  const size_t eoff_out = (size_t)eidx * N * K;
  const int kr = tid >> 4;
  const int nc = (tid & 15) * 4;
#pragma unroll
  for (int it = 0; it < 4; ++it) {
    int k = k0 + kr + it * 16;
    int n = n0 + nc;
    float4 v = {0.f, 0.f, 0.f, 0.f};
    if (k < K && n + 4 <= N) v = *(const float4*)(in + eoff_in + (size_t)k * N + n);
    T[nc + 0][kr + it * 16] = bf16bits(v.x);
    T[nc + 1][kr + it * 16] = bf16bits(v.y);
    T[nc + 2][kr + it * 16] = bf16bits(v.z);
    T[nc + 3][kr + it * 16] = bf16bits(v.w);
  }
  __syncthreads();
  const int nr = tid >> 2;
  const int kc = tid & 3;
#pragma unroll
  for (int it = 0; it < 2; ++it) {
    int kloc = kc * 16 + it * 8;
    int n = n0 + nr, k = k0 + kloc;
    if (n < N && k + 8 <= K)
      *(uint4*)(out + eoff_out + (size_t)n * K + k) = *(const uint4*)&T[nr][kloc];
  }
}

// ======================================================================
// GEMM1 (256Mx128N, BK=32, QUAD-buffer, rowpair-128B layout, 8 waves):
//   h = silu(Xe*Wg) .* (Xe*Wu)
// Pipelined fragments: tile t's MFMA overlaps tile t+1's ds_reads.
// Per K-tile: {stage t+3 | read-ahead frags t+1 | lgkm(12) | 32 MFMA |
//              vmcnt(4) | barrier}
// Invariant at iter t start: tiles <= t+1 landed, stage {t+2} in flight.
// LDS 128KB: A[4][16KB]@0, Bg[4][8KB]@64K, Bu[4][8KB]@96K
// ======================================================================
#define GU_READ(SET, RB) { \
  char* Ab_  = sm + (RB) * 16384; \
  char* Bgb_ = sm + 65536 + (RB) * 8192; \
  char* Bub_ = sm + 98304 + (RB) * 8192; \
  _Pragma("unroll") for (int i_ = 0; i_ < 4; ++i_) aR##SET[i_]  = *(const bf16x8*)(Ab_ + aoff[i_]); \
  _Pragma("unroll") for (int j_ = 0; j_ < 4; ++j_) bgR##SET[j_] = *(const bf16x8*)(Bgb_ + boff[j_]); \
  _Pragma("unroll") for (int j_ = 0; j_ < 4; ++j_) buR##SET[j_] = *(const bf16x8*)(Bub_ + boff[j_]); \
}
#define GU_MFMA(SET) { \
  _Pragma("unroll") for (int j_ = 0; j_ < 4; ++j_) \
    _Pragma("unroll") for (int i_ = 0; i_ < 4; ++i_) \
      accG[i_][j_] = __builtin_amdgcn_mfma_f32_16x16x32_bf16(aR##SET[i_], bgR##SET[j_], accG[i_][j_], 0, 0, 0); \
  _Pragma("unroll") for (int j_ = 0; j_ < 4; ++j_) \
    _Pragma("unroll") for (int i_ = 0; i_ < 4; ++i_) \
      accU[i_][j_] = __builtin_amdgcn_mfma_f32_16x16x32_bf16(aR##SET[i_], buR##SET[j_], accU[i_][j_], 0, 0, 0); \
}
#define GU_BODY(T, CUR, NXT) { \
  const int t_ = (T); \
  if (t_ + 3 < NT) { \
    const int kk_ = (t_ + 3) * 32; const int w_ = (t_ + 3) & 3; \
    gload16(srcA[0] + kk_, (ushort*)(sm + w_ * 16384 + dstw)); \
    gload16(srcA[1] + kk_, (ushort*)(sm + w_ * 16384 + 8192 + dstw)); \
    gload16(srcBg + kk_, (ushort*)(sm + 65536 + w_ * 8192 + dstw)); \
    gload16(srcBu + kk_, (ushort*)(sm + 98304 + w_ * 8192 + dstw)); \
  } \
  if (t_ + 1 < NT) { GU_READ(NXT, (t_ + 1) & 3); LGKM(12); } else { LGKM(0); } \
  SCHED0(); SETPRIO(1); \
  GU_MFMA(CUR); \
  SETPRIO(0); SCHED0(); \
  if (t_ + 3 < NT) { WAITV(4); } else if (t_ + 2 < NT) { WAITV(0); } \
  BARRIER(); \
}

__global__ __launch_bounds__(512, 2) void gemm_gateup3(
    const ushort* __restrict__ xb, const ushort* __restrict__ wgt,
    const ushort* __restrict__ wut, const int* __restrict__ tok_slot,
    ushort* __restrict__ h)
{
  __shared__ __align__(16) char sm[131072];
  const int tid = threadIdx.x, lane = tid & 63, wid = tid >> 6;
  const int wr = wid >> 1, wc = wid & 1;
  const int l15 = lane & 15, l4 = lane >> 4;

  // XCD swizzle: 440 blocks = 8 XCDs x 55 (one expert: 5 mt x 11 nt)
  int wgid = (blockIdx.x & 7) * 55 + (blockIdx.x >> 3);
  const int e = wgid / 55;
  const int rem = wgid - e * 55;
  const int mt = rem / 11, nt = rem - (rem / 11) * 11;
  const int n0 = nt * 128;

  const ushort* srcA[2]; const ushort* srcBg; const ushort* srcBu;
#pragma unroll
  for (int c = 0; c < 2; ++c) {
    int o = c * 8192 + wid * 1024 + lane * 16;
    int row, ko; rp_src(o, row, ko);
    int tk = tok_slot[e * CAP + mt * 256 + row];
    if (tk < 0) tk = 0;                        // finite garbage; discarded
    srcA[c] = xb + (size_t)tk * DH + ko;
  }
  {
    int o = wid * 1024 + lane * 16;
    int row, ko; rp_src(o, row, ko);
    int n = n0 + row; if (n > DF - 1) n = DF - 1;
    srcBg = wgt + ((size_t)e * DF + n) * DH + ko;
    srcBu = wut + ((size_t)e * DF + n) * DH + ko;
  }
  int aoff[4], boff[4];
#pragma unroll
  for (int i = 0; i < 4; ++i) aoff[i] = rp_off(wr * 64 + i * 16 + l15, l4);
#pragma unroll
  for (int j = 0; j < 4; ++j) boff[j] = rp_off(wc * 64 + j * 16 + l15, l4);
  const int dstw = wid * 1024;

  f32x4 accG[4][4], accU[4][4];
#pragma unroll
  for (int i = 0; i < 4; ++i)
#pragma unroll
    for (int j = 0; j < 4; ++j) {
      accG[i][j] = (f32x4){0.f, 0.f, 0.f, 0.f};
      accU[i][j] = (f32x4){0.f, 0.f, 0.f, 0.f};
    }

  const int NT = DH / 32;  // 64
#pragma unroll
  for (int t0 = 0; t0 < 3; ++t0) {
    int kk = t0 * 32;
    gload16(srcA[0] + kk, (ushort*)(sm + t0 * 16384 + dstw));
    gload16(srcA[1] + kk, (ushort*)(sm + t0 * 16384 + 8192 + dstw));
    gload16(srcBg   + kk, (ushort*)(sm + 65536 + t0 * 8192 + dstw));
    gload16(srcBu   + kk, (ushort*)(sm + 98304 + t0 * 8192 + dstw));
  }
  WAITV(4);       // tiles 0,1 landed; {2} in flight
  BARRIER();

  bf16x8 aR0[4], bgR0[4], buR0[4], aR1[4], bgR1[4], buR1[4];
  GU_READ(0, 0);  // frags tile0

  for (int t = 0; t < NT; t += 2) {
    GU_BODY(t, 0, 1);
    GU_BODY(t + 1, 1, 0);
  }

  // epilogue: SwiGLU -> h
  const size_t rowbase = (size_t)(e * CAP + mt * 256 + wr * 64);
#pragma unroll
  for (int j = 0; j < 4; ++j) {
    int col = n0 + wc * 64 + j * 16 + l15;
    if (col < DF) {
#pragma unroll
      for (int i = 0; i < 4; ++i)
#pragma unroll
        for (int r2 = 0; r2 < 4; ++r2) {
          size_t row = rowbase + i * 16 + l4 * 4 + r2;
          float gv = accG[i][j][r2], uv = accU[i][j][r2];
          h[row * DF + col] = bf16bits(gv / (1.f + __expf(-gv)) * uv);
        }
    }
  }
}

// ======================================================================
// GEMM2 (256Mx128N, BK=32, QUAD-buffer, rowpair-128B, 8 waves, pipelined
// fragments): y[token] = (H*Wd)*score.  NT = DF/32 = 43 (odd -> tail body).
// LDS 98KB: A[4][16KB]@0, B[4][8KB]@64K, tokc@96K, scc@97K
// ======================================================================
#define DN_READ(SET, RB) { \
  char* Ab_ = sm + (RB) * 16384; \
  char* Bb_ = sm + 65536 + (RB) * 8192; \
  _Pragma("unroll") for (int i_ = 0; i_ < 4; ++i_) aR##SET[i_] = *(const bf16x8*)(Ab_ + aoff[i_]); \
  _Pragma("unroll") for (int j_ = 0; j_ < 4; ++j_) bR##SET[j_] = *(const bf16x8*)(Bb_ + boff[j_]); \
}
#define DN_MFMA(SET) { \
  _Pragma("unroll") for (int j_ = 0; j_ < 4; ++j_) \
    _Pragma("unroll") for (int i_ = 0; i_ < 4; ++i_) \
      acc[i_][j_] = __builtin_amdgcn_mfma_f32_16x16x32_bf16(aR##SET[i_], bR##SET[j_], acc[i_][j_], 0, 0, 0); \
}
#define DN_BODY(T, CUR, NXT) { \
  const int t_ = (T); \
  if (t_ + 3 < NT) { \
    const int kk_ = (t_ + 3) * 32; const int w_ = (t_ + 3) & 3; \
    gload16(srcA[0] + kk_, (ushort*)(sm + w_ * 16384 + dstw)); \
    gload16(srcA[1] + kk_, (ushort*)(sm + w_ * 16384 + 8192 + dstw)); \
    gload16(srcB + kk_, (ushort*)(sm + 65536 + w_ * 8192 + dstw)); \
  } \
  if (t_ + 1 < NT) { DN_READ(NXT, (t_ + 1) & 3); LGKM(8); } else { LGKM(0); } \
  SCHED0(); SETPRIO(1); \
  DN_MFMA(CUR); \
  SETPRIO(0); SCHED0(); \
  if (t_ + 3 < NT) { WAITV(3); } else if (t_ + 2 < NT) { WAITV(0); } \
  BARRIER(); \
}

__global__ __launch_bounds__(512, 2) void gemm_down3(
    const ushort* __restrict__ h, const ushort* __restrict__ wdt,
    const int* __restrict__ tok_slot, const float* __restrict__ scores,
    float* __restrict__ y)
{
  __shared__ __align__(16) char sm[100352];
  int* tokc = (int*)(sm + 98304);
  float* scc = (float*)(sm + 99328);
  const int tid = threadIdx.x, lane = tid & 63, wid = tid >> 6;
  const int wr = wid >> 1, wc = wid & 1;
  const int l15 = lane & 15, l4 = lane >> 4;

  // XCD swizzle: 640 blocks = 8 XCDs x 80 (one expert: 5 mt x 16 nt)
  int wgid = (blockIdx.x & 7) * 80 + (blockIdx.x >> 3);
  const int e = wgid / 80;
  const int rem = wgid - e * 80;
  const int mt = rem / 16, nt = rem & 15;
  const int n0 = nt * 128;

  if (tid < 256) {
    int tk = tok_slot[e * CAP + mt * 256 + tid];
    tokc[tid] = tk;
    scc[tid] = (tk >= 0) ? scores[tk] : 0.f;
  }
  __syncthreads();

  const size_t hrow0 = (size_t)(e * CAP + mt * 256);
  const ushort* srcA[2]; const ushort* srcB;
#pragma unroll
  for (int c = 0; c < 2; ++c) {
    int o = c * 8192 + wid * 1024 + lane * 16;
    int row, ko; rp_src(o, row, ko);
    srcA[c] = h + (hrow0 + row) * DF + ko;
  }
  {
    int o = wid * 1024 + lane * 16;
    int row, ko; rp_src(o, row, ko);
    srcB = wdt + ((size_t)e * DH + n0 + row) * DF + ko;
  }
  int aoff[4], boff[4];
#pragma unroll
  for (int i = 0; i < 4; ++i) aoff[i] = rp_off(wr * 64 + i * 16 + l15, l4);
#pragma unroll
  for (int j = 0; j < 4; ++j) boff[j] = rp_off(wc * 64 + j * 16 + l15, l4);
  const int dstw = wid * 1024;

  f32x4 acc[4][4];
#pragma unroll
  for (int i = 0; i < 4; ++i)
#pragma unroll
    for (int j = 0; j < 4; ++j) acc[i][j] = (f32x4){0.f, 0.f, 0.f, 0.f};

  const int NT = DF / 32;  // 43
#pragma unroll
  for (int t0 = 0; t0 < 3; ++t0) {
    int kk = t0 * 32;
    gload16(srcA[0] + kk, (ushort*)(sm + t0 * 16384 + dstw));
    gload16(srcA[1] + kk, (ushort*)(sm + t0 * 16384 + 8192 + dstw));
    gload16(srcB    + kk, (ushort*)(sm + 65536 + t0 * 8192 + dstw));
  }
  WAITV(3);       // tiles 0,1 landed; {2} in flight
  BARRIER();

  bf16x8 aR0[4], bR0[4], aR1[4], bR1[4];
  DN_READ(0, 0);

  for (int t = 0; t < NT - 1; t += 2) {   // 21 pairs: t = 0..41
    DN_BODY(t, 0, 1);
    DN_BODY(t + 1, 1, 0);
  }
  DN_BODY(NT - 1, 0, 1);                  // tail t = 42 (uses set 0)

  // epilogue: scatter * score
  int tkr[4][4]; float sr[4][4];
#pragma unroll
  for (int i = 0; i < 4; ++i)
#pragma unroll
    for (int r = 0; r < 4; ++r) {
      int rl = wr * 64 + i * 16 + l4 * 4 + r;
      tkr[i][r] = tokc[rl];
      sr[i][r]  = scc[rl];
    }
#pragma unroll
  for (int j = 0; j < 4; ++j) {
    int col = n0 + wc * 64 + j * 16 + l15;
#pragma unroll
    for (int i = 0; i < 4; ++i)
#pragma unroll
      for (int r = 0; r < 4; ++r)
        if (tkr[i][r] >= 0)
          y[(size_t)tkr[i][r] * DH + col] = acc[i][j][r] * sr[i][r];
  }
}

extern "C" void kernel_launch(void* const* d_in, const int* in_sizes, int n_in,
                              void* d_out, int out_size, void* d_ws, size_t ws_size,
                              hipStream_t stream) {
  const float* x   = (const float*)d_in[0];
  const int*   idx = (const int*)d_in[1];
  const float* sc  = (const float*)d_in[2];
  const float* wg  = (const float*)d_in[3];
  const float* wu  = (const float*)d_in[4];
  const float* wd  = (const float*)d_in[5];
  float* y = (float*)d_out;

  // ws layout (~152 MB; wdt shares wgt region? NO - wd transpose now runs
  // before gateup, so wdt needs its own region)
  const size_t OFF_KEEP = 40960;
  const size_t OFF_H    = 73728;
  const size_t SZ_H     = (size_t)NE * CAP * DF * 2;   // 28,180,480
  const size_t OFF_XB   = OFF_H + SZ_H;
  const size_t SZ_XB    = (size_t)NTOK * DH * 2;       // 33,554,432
  const size_t OFF_WGT  = OFF_XB + SZ_XB;
  const size_t SZ_W     = (size_t)NE * DH * DF * 2;    // 45,088,768
  const size_t OFF_WUT  = OFF_WGT + SZ_W;
  const size_t OFF_WDT  = OFF_WUT + SZ_W;              // total ~197 MB

  int* tok_slot = (int*)d_ws;
  int* tok_keep = (int*)((char*)d_ws + OFF_KEEP);
  ushort* hbuf = (ushort*)((char*)d_ws + OFF_H);
  ushort* xb   = (ushort*)((char*)d_ws + OFF_XB);
  ushort* wgt  = (ushort*)((char*)d_ws + OFF_WGT);
  ushort* wut  = (ushort*)((char*)d_ws + OFF_WUT);
  ushort* wdt  = (ushort*)((char*)d_ws + OFF_WDT);

  hipLaunchKernelGGL(routing_kernel, dim3(1), dim3(256), 0, stream, idx, tok_slot, tok_keep);
  hipLaunchKernelGGL(xconv_zero, dim3(NTOK), dim3(256), 0, stream, x, tok_keep, xb, y);
  hipLaunchKernelGGL(transpose_all, dim3(32, 32, 24), dim3(256), 0, stream,
                     wg, wu, wd, wgt, wut, wdt);
  hipLaunchKernelGGL(gemm_gateup3, dim3(440), dim3(512), 0, stream,
                     xb, wgt, wut, tok_slot, hbuf);
  hipLaunchKernelGGL(gemm_down3, dim3(640), dim3(512), 0, stream,
                     hbuf, wdt, tok_slot, sc, y);
}